// Round 3
// baseline (990.714 us; speedup 1.0000x reference)
//
#include <hip/hip_runtime.h>
#include <hip/hip_bf16.h>

// ---- problem constants ----
#define MOD   3
#define BATCH 65536
#define EDIM  512
#define ADIM  256
#define FEAT  1536   // MOD*EDIM

// ---- types ----
typedef __attribute__((ext_vector_type(8))) short   s16x8;
typedef __attribute__((ext_vector_type(8))) __bf16  bf16x8;
typedef __attribute__((ext_vector_type(4))) float   f32x4;
typedef __attribute__((ext_vector_type(4))) unsigned short u16x4;

__device__ __forceinline__ float b2f(unsigned short u) {
    union { unsigned int ui; float f; } c; c.ui = ((unsigned int)u) << 16; return c.f;
}
__device__ __forceinline__ unsigned short f2b(float f) {
    __hip_bfloat16 h = __float2bfloat16(f);
    return __builtin_bit_cast(unsigned short, h);
}

// async global->LDS, 16B per lane (wave-uniform LDS base + lane*16)
__device__ __forceinline__ void glds16(const unsigned short* g, unsigned short* l) {
    __builtin_amdgcn_global_load_lds(
        (const __attribute__((address_space(1))) void*)g,
        (__attribute__((address_space(3))) void*)l, 16, 0, 0);
}

// ============ kernel 0: x f32 -> bf16 bits ============
__global__ __launch_bounds__(256) void k_convert_x(const float* __restrict__ x,
                                                   unsigned short* __restrict__ xb, int n4) {
    int i = blockIdx.x * blockDim.x + threadIdx.x;
    int stride = gridDim.x * blockDim.x;
    for (; i < n4; i += stride) {
        f32x4 v = *((const f32x4*)x + i);
        u16x4 o;
        for (int j = 0; j < 4; ++j) o[j] = f2b(v[j]);
        *((u16x4*)xb + i) = o;
    }
}

// ============ kernel 1: weight prep ============
__global__ __launch_bounds__(256) void k_prep_w(const float* __restrict__ Wq,
                                                const float* __restrict__ Wk,
                                                const float* __restrict__ Wt,
                                                unsigned short* __restrict__ wqk,
                                                unsigned short* __restrict__ wtt2) {
    int i = blockIdx.x * blockDim.x + threadIdx.x;
    int stride = gridDim.x * blockDim.x;
    for (int idx = i; idx < MOD * EDIM * EDIM; idx += stride) {
        int m = idx / (EDIM * EDIM); int r = idx % (EDIM * EDIM);
        int n = r / EDIM; int e = r % EDIM;
        float f = (n < ADIM) ? Wq[(m * EDIM + e) * ADIM + n]
                             : Wk[(m * EDIM + e) * ADIM + (n - ADIM)];
        wqk[idx] = f2b(f);
    }
    for (int idx = i; idx < MOD * 1024 * EDIM; idx += stride) {
        int k = idx / (1024 * EDIM); int r = idx % (1024 * EDIM);
        int n = r / EDIM; int e = r % EDIM;
        int q = (n < EDIM) ? (k + 1) % 3 : (k + 2) % 3;
        int f = (n < EDIM) ? n : n - EDIM;
        wtt2[idx] = f2b(Wt[((size_t)(q * 3 + k) * EDIM + e) * EDIM + f]);
    }
}

// ---- GEMM geometry: 128x128 tile, BK=32, 4 waves (2x2), 4x4 frags, 3-buffer pipeline ----
#define BM  128
#define BN  128
#define BK  32
#define NKT 16            // K tiles = 512/32
#define BUFE 4096         // elements per LDS buffer (128*32)

__device__ __forceinline__ int swz4(int row) { return (row ^ (row >> 2)) & 3; }

struct PipeCtx {
    const unsigned short *gA0, *gA1, *gB0, *gB1;
    unsigned short *As, *Bs;
    int lo0, lo1;
    int offA[4], offB[4];
};

__device__ __forceinline__ void pipe_init(PipeCtx& c,
                                          const unsigned short* Ag, const unsigned short* Bg,
                                          unsigned short* As, unsigned short* Bs) {
    const int t = threadIdx.x, lane = t & 63, wid = t >> 6;
    const int wr = (wid >> 1) * 64, wc = (wid & 1) * 64;
    const int r0 = wid * 16 + (lane >> 2), r1 = r0 + 64;
    c.gA0 = Ag + (size_t)r0 * EDIM + (((lane & 3) ^ swz4(r0)) * 8);
    c.gA1 = Ag + (size_t)r1 * EDIM + (((lane & 3) ^ swz4(r1)) * 8);
    c.gB0 = Bg + (size_t)r0 * EDIM + (((lane & 3) ^ swz4(r0)) * 8);
    c.gB1 = Bg + (size_t)r1 * EDIM + (((lane & 3) ^ swz4(r1)) * 8);
    c.As = As; c.Bs = Bs;
    c.lo0 = wid * 512; c.lo1 = 2048 + wid * 512;
    const int rr = lane & 15, cg = lane >> 4;
#pragma unroll
    for (int i = 0; i < 4; ++i) {
        int ra = wr + i * 16 + rr;
        c.offA[i] = ra * BK + ((cg ^ swz4(ra)) * 8);
        int rb = wc + i * 16 + rr;
        c.offB[i] = rb * BK + ((cg ^ swz4(rb)) * 8);
    }
}

__device__ __forceinline__ void pipe_stage(const PipeCtx& c, int kt, int buf) {
    glds16(c.gA0 + kt * BK, c.As + buf * BUFE + c.lo0);
    glds16(c.gA1 + kt * BK, c.As + buf * BUFE + c.lo1);
    glds16(c.gB0 + kt * BK, c.Bs + buf * BUFE + c.lo0);
    glds16(c.gB1 + kt * BK, c.Bs + buf * BUFE + c.lo1);
}

__device__ __forceinline__ void pipe_compute(const PipeCtx& c, int buf, f32x4 (&acc)[4][4]) {
    const unsigned short* ab = c.As + buf * BUFE;
    const unsigned short* bb = c.Bs + buf * BUFE;
    s16x8 af[4], bfr[4];
#pragma unroll
    for (int i = 0; i < 4; ++i) af[i]  = *(const s16x8*)(ab + c.offA[i]);
#pragma unroll
    for (int j = 0; j < 4; ++j) bfr[j] = *(const s16x8*)(bb + c.offB[j]);
    __builtin_amdgcn_s_setprio(1);
#pragma unroll
    for (int i = 0; i < 4; ++i)
#pragma unroll
        for (int j = 0; j < 4; ++j)
            acc[i][j] = __builtin_amdgcn_mfma_f32_16x16x32_bf16(
                __builtin_bit_cast(bf16x8, af[i]), __builtin_bit_cast(bf16x8, bfr[j]),
                acc[i][j], 0, 0, 0);
    __builtin_amdgcn_s_setprio(0);
}

// 3-buffer, stage-2-ahead, counted-vmcnt main loop.
// Invariant at tile t's wait: outstanding allowed = loads of stages t+1,t+2 (=8)
// => stage(t) has landed; barrier publishes this across waves.
__device__ __forceinline__ void gemm_pipe_k512(const unsigned short* __restrict__ Ag,
                                               const unsigned short* __restrict__ Bg,
                                               unsigned short* __restrict__ As,
                                               unsigned short* __restrict__ Bs,
                                               f32x4 (&acc)[4][4]) {
    PipeCtx c;
    pipe_init(c, Ag, Bg, As, Bs);
    pipe_stage(c, 0, 0);
    pipe_stage(c, 1, 1);
    asm volatile("s_waitcnt vmcnt(4)" ::: "memory");
    __builtin_amdgcn_s_barrier();
    int bc = 0, bn = 2;
#pragma unroll 1
    for (int kt = 0; kt < NKT - 2; ++kt) {
        pipe_stage(c, kt + 2, bn);
        asm volatile("s_waitcnt vmcnt(8)" ::: "memory");
        __builtin_amdgcn_s_barrier();
        pipe_compute(c, bc, acc);
        __builtin_amdgcn_s_barrier();
        bc = (bc == 2) ? 0 : bc + 1;
        bn = (bn == 2) ? 0 : bn + 1;
    }
    // tile NKT-2
    asm volatile("s_waitcnt vmcnt(4)" ::: "memory");
    __builtin_amdgcn_s_barrier();
    pipe_compute(c, bc, acc);
    __builtin_amdgcn_s_barrier();
    bc = (bc == 2) ? 0 : bc + 1;
    // tile NKT-1
    asm volatile("s_waitcnt vmcnt(0)" ::: "memory");
    __builtin_amdgcn_s_barrier();
    pipe_compute(c, bc, acc);
}

// ============ kernel 2: proj = X_m @ [Wq|Wk]_m + bias, bf16 out ============
__global__ __launch_bounds__(256) void k_gemm_proj(const unsigned short* __restrict__ xb,
                                                   const unsigned short* __restrict__ wqk,
                                                   const float* __restrict__ bq,
                                                   const float* __restrict__ bk,
                                                   unsigned short* __restrict__ proj) {
    __shared__ __align__(16) unsigned short As[3 * BUFE];
    __shared__ __align__(16) unsigned short Bs[3 * BUFE];
    int l = (blockIdx.x & 7) * 768 + (blockIdx.x >> 3);   // XCD-chunked, nwg=6144
    int ct = l & 3, rt = (l >> 2) & 511, m = l >> 11;
    int row0 = rt * BM, col0 = ct * BN;
    f32x4 acc[4][4];
#pragma unroll
    for (int i = 0; i < 4; ++i) for (int j = 0; j < 4; ++j) acc[i][j] = (f32x4)0.f;
    gemm_pipe_k512(xb + ((size_t)m * BATCH + row0) * EDIM,
                   wqk + ((size_t)m * EDIM + col0) * EDIM, As, Bs, acc);
    int lane = threadIdx.x & 63, wid = threadIdx.x >> 6;
    int wr = (wid >> 1) * 64, wc = (wid & 1) * 64;
#pragma unroll
    for (int j = 0; j < 4; ++j) {
        int col = col0 + wc + j * 16 + (lane & 15);
        float bias = (col < ADIM) ? bq[m * ADIM + col] : bk[m * ADIM + col - ADIM];
#pragma unroll
        for (int i = 0; i < 4; ++i) {
            int rbase = row0 + wr + i * 16 + (lane >> 4) * 4;
#pragma unroll
            for (int r = 0; r < 4; ++r)
                proj[((size_t)m * BATCH + rbase + r) * EDIM + col] = f2b(acc[i][j][r] + bias);
        }
    }
}

// ============ kernel 3: scores + softmax -> alpha[q*2+ki][b], k=(q+1+ki)%3 ============
__global__ __launch_bounds__(256) void k_scores(const unsigned short* __restrict__ proj,
                                                const float* __restrict__ v,
                                                float* __restrict__ alpha) {
    int wid = threadIdx.x >> 6, lane = threadIdx.x & 63;
    size_t b = (size_t)blockIdx.x * 4 + wid;
    float qp[3][4], kp[3][4], vq[3][4];
    for (int m = 0; m < 3; ++m) {
        const unsigned short* p = proj + ((size_t)m * BATCH + b) * EDIM;
        u16x4 uq = *(const u16x4*)(p + lane * 4);
        u16x4 uk = *(const u16x4*)(p + ADIM + lane * 4);
        f32x4 vv = *((const f32x4*)(v + m * ADIM) + lane);
        for (int j = 0; j < 4; ++j) { qp[m][j] = b2f(uq[j]); kp[m][j] = b2f(uk[j]); vq[m][j] = vv[j]; }
    }
    for (int q = 0; q < 3; ++q) {
        float s[2];
        for (int ki = 0; ki < 2; ++ki) {
            int k = (q + 1 + ki) % 3;
            float a = 0.f;
            for (int j = 0; j < 4; ++j) a += vq[q][j] * tanhf(qp[q][j] + kp[k][j]);
            for (int off = 32; off; off >>= 1) a += __shfl_xor(a, off, 64);
            s[ki] = a;
        }
        if (lane == 0) {
            float mx = fmaxf(s[0], s[1]);
            float e0 = expf(s[0] - mx), e1 = expf(s[1] - mx);
            float inv = 1.f / (e0 + e1);
            alpha[(size_t)(q * 2 + 0) * BATCH + b] = e0 * inv;
            alpha[(size_t)(q * 2 + 1) * BATCH + b] = e1 * inv;
        }
    }
}

// ============ kernel 4: Y[k] = X_k @ wtt2[k]  (N=1024 pure GEMM) ============
__global__ __launch_bounds__(256) void k_gemm_y(const unsigned short* __restrict__ xb,
                                                const unsigned short* __restrict__ wtt2,
                                                unsigned short* __restrict__ y) {
    __shared__ __align__(16) unsigned short As[3 * BUFE];
    __shared__ __align__(16) unsigned short Bs[3 * BUFE];
    int l = (blockIdx.x & 7) * 1536 + (blockIdx.x >> 3);  // XCD-chunked, nwg=12288
    int ct = l & 7, rt = (l >> 3) & 511, k = l >> 12;
    int row0 = rt * BM, col0 = ct * BN;
    f32x4 acc[4][4];
#pragma unroll
    for (int i = 0; i < 4; ++i) for (int j = 0; j < 4; ++j) acc[i][j] = (f32x4)0.f;
    gemm_pipe_k512(xb + ((size_t)k * BATCH + row0) * EDIM,
                   wtt2 + ((size_t)k * 1024 + col0) * EDIM, As, Bs, acc);
    int lane = threadIdx.x & 63, wid = threadIdx.x >> 6;
    int wr = (wid >> 1) * 64, wc = (wid & 1) * 64;
    int p  = (ct < 4) ? (((k + 1) % 3) * 2 + 1) : (((k + 2) % 3) * 2 + 0);
    int cb = (ct < 4) ? col0 : (col0 - EDIM);
#pragma unroll
    for (int j = 0; j < 4; ++j) {
        int col = cb + wc + j * 16 + (lane & 15);
#pragma unroll
        for (int i = 0; i < 4; ++i) {
            int rbase = row0 + wr + i * 16 + (lane >> 4) * 4;
#pragma unroll
            for (int r = 0; r < 4; ++r)
                y[((size_t)p * BATCH + rbase + r) * EDIM + col] = f2b(acc[i][j][r]);
        }
    }
}

// ============ kernel 5: out = LN(xb + a0*(Y0+bt0) + a1*(Y1+bt1)) ============
__global__ __launch_bounds__(192) void k_fuse_ln(const unsigned short* __restrict__ xb,
                                                 const unsigned short* __restrict__ y,
                                                 const float* __restrict__ alpha,
                                                 const float* __restrict__ bt,
                                                 const float* __restrict__ gamma,
                                                 const float* __restrict__ beta,
                                                 float* __restrict__ out) {
    __shared__ float red[2][3];
    int b = blockIdx.x, t = threadIdx.x, m = t >> 6, lane = t & 63;
    int e0 = lane * 8;
    float a0 = alpha[(size_t)(m * 2 + 0) * BATCH + b];
    float a1 = alpha[(size_t)(m * 2 + 1) * BATCH + b];
    s16x8 xv = *(const s16x8*)(xb + ((size_t)m * BATCH + b) * EDIM + e0);
    s16x8 y0 = *(const s16x8*)(y + ((size_t)(m * 2 + 0) * BATCH + b) * EDIM + e0);
    s16x8 y1 = *(const s16x8*)(y + ((size_t)(m * 2 + 1) * BATCH + b) * EDIM + e0);
    int kA = (m + 1) % 3, kB = (m + 2) % 3;
    const float* bA = bt + (size_t)(m * 3 + kA) * EDIM + e0;
    const float* bB = bt + (size_t)(m * 3 + kB) * EDIM + e0;
    f32x4 bA0 = *(const f32x4*)bA, bA1 = *(const f32x4*)(bA + 4);
    f32x4 bB0 = *(const f32x4*)bB, bB1 = *(const f32x4*)(bB + 4);
    float v[8]; float s = 0.f, s2 = 0.f;
#pragma unroll
    for (int j = 0; j < 8; ++j) {
        float ba = (j < 4) ? bA0[j] : bA1[j - 4];
        float bb = (j < 4) ? bB0[j] : bB1[j - 4];
        float vv = b2f((unsigned short)xv[j]) + a0 * (b2f((unsigned short)y0[j]) + ba)
                                             + a1 * (b2f((unsigned short)y1[j]) + bb);
        v[j] = vv; s += vv; s2 += vv * vv;
    }
    for (int off = 32; off; off >>= 1) { s += __shfl_xor(s, off, 64); s2 += __shfl_xor(s2, off, 64); }
    if (lane == 0) { red[0][m] = s; red[1][m] = s2; }
    __syncthreads();
    float S = red[0][0] + red[0][1] + red[0][2];
    float S2 = red[1][0] + red[1][1] + red[1][2];
    float mu  = S * (1.f / 1536.f);
    float var = S2 * (1.f / 1536.f) - mu * mu;
    float rs  = rsqrtf(var + 1e-5f);
    int f0 = m * EDIM + e0;
    f32x4 g0 = *(const f32x4*)(gamma + f0), g1 = *(const f32x4*)(gamma + f0 + 4);
    f32x4 be0 = *(const f32x4*)(beta + f0), be1 = *(const f32x4*)(beta + f0 + 4);
    f32x4 o0, o1;
#pragma unroll
    for (int j = 0; j < 4; ++j) {
        o0[j] = (v[j]     - mu) * rs * g0[j] + be0[j];
        o1[j] = (v[j + 4] - mu) * rs * g1[j] + be1[j];
    }
    float* op = out + (size_t)b * FEAT + f0;
    *(f32x4*)op = o0; *(f32x4*)(op + 4) = o1;
}

// ============ launcher ============
extern "C" void kernel_launch(void* const* d_in, const int* in_sizes, int n_in,
                              void* d_out, int out_size, void* d_ws, size_t ws_size,
                              hipStream_t stream) {
    const float* x     = (const float*)d_in[0];
    const float* Wq    = (const float*)d_in[1];
    const float* bq    = (const float*)d_in[2];
    const float* Wk    = (const float*)d_in[3];
    const float* bk    = (const float*)d_in[4];
    const float* v     = (const float*)d_in[5];
    const float* Wt    = (const float*)d_in[6];
    const float* bt    = (const float*)d_in[7];
    const float* gamma = (const float*)d_in[8];
    const float* beta  = (const float*)d_in[9];
    float* out = (float*)d_out;

    char* ws = (char*)d_ws;
    unsigned short* wqk   = (unsigned short*)(ws);
    unsigned short* wtt2  = (unsigned short*)(ws + 1572864);
    float*          alpha = (float*)        (ws + 4718592);
    unsigned short* xb    = (unsigned short*)(ws + 6291456);
    unsigned short* y     = (unsigned short*)(ws + 207618048);
    unsigned short* proj  = y;  // proj fully consumed by k_scores before k_gemm_y writes y

    k_convert_x<<<4096, 256, 0, stream>>>(x, xb, (MOD * BATCH * EDIM) / 4);
    k_prep_w   <<<2048, 256, 0, stream>>>(Wq, Wk, Wt, wqk, wtt2);
    k_gemm_proj<<<6144, 256, 0, stream>>>(xb, wqk, bq, bk, proj);
    k_scores   <<<16384, 256, 0, stream>>>(proj, v, alpha);
    k_gemm_y   <<<12288, 256, 0, stream>>>(xb, wtt2, y);
    k_fuse_ln  <<<65536, 192, 0, stream>>>(xb, y, alpha, bt, gamma, beta, out);
}

// Round 4
// 899.735 us; speedup vs baseline: 1.1011x; 1.1011x over previous
//
#include <hip/hip_runtime.h>
#include <hip/hip_bf16.h>

// ---- problem constants ----
#define MOD   3
#define BATCH 65536
#define EDIM  512
#define ADIM  256
#define FEAT  1536   // MOD*EDIM

// ---- types ----
typedef __attribute__((ext_vector_type(8))) short   s16x8;
typedef __attribute__((ext_vector_type(8))) __bf16  bf16x8;
typedef __attribute__((ext_vector_type(4))) float   f32x4;
typedef __attribute__((ext_vector_type(4))) unsigned short u16x4;

__device__ __forceinline__ float b2f(unsigned short u) {
    union { unsigned int ui; float f; } c; c.ui = ((unsigned int)u) << 16; return c.f;
}
__device__ __forceinline__ unsigned short f2b(float f) {
    __hip_bfloat16 h = __float2bfloat16(f);
    return __builtin_bit_cast(unsigned short, h);
}

// async global->LDS, 16B per lane (wave-uniform LDS base; HW adds lane*16)
__device__ __forceinline__ void glds16(const unsigned short* g, unsigned short* l) {
    __builtin_amdgcn_global_load_lds(
        (const __attribute__((address_space(1))) void*)g,
        (__attribute__((address_space(3))) void*)l, 16, 0, 0);
}

#define WAITV(N) asm volatile("s_waitcnt vmcnt(%0)" :: "i"(N) : "memory")
__device__ __forceinline__ void BAR() {
    asm volatile("" ::: "memory");
    __builtin_amdgcn_s_barrier();
    asm volatile("" ::: "memory");
}

// ============ kernel 0: x f32 -> bf16 bits ============
__global__ __launch_bounds__(256) void k_convert_x(const float* __restrict__ x,
                                                   unsigned short* __restrict__ xb, int n4) {
    int i = blockIdx.x * blockDim.x + threadIdx.x;
    int stride = gridDim.x * blockDim.x;
    for (; i < n4; i += stride) {
        f32x4 v = *((const f32x4*)x + i);
        u16x4 o;
        for (int j = 0; j < 4; ++j) o[j] = f2b(v[j]);
        *((u16x4*)xb + i) = o;
    }
}

// ============ kernel 1: weight prep ============
__global__ __launch_bounds__(256) void k_prep_w(const float* __restrict__ Wq,
                                                const float* __restrict__ Wk,
                                                const float* __restrict__ Wt,
                                                unsigned short* __restrict__ wqk,
                                                unsigned short* __restrict__ wtt2) {
    int i = blockIdx.x * blockDim.x + threadIdx.x;
    int stride = gridDim.x * blockDim.x;
    for (int idx = i; idx < MOD * EDIM * EDIM; idx += stride) {
        int m = idx / (EDIM * EDIM); int r = idx % (EDIM * EDIM);
        int n = r / EDIM; int e = r % EDIM;
        float f = (n < ADIM) ? Wq[(m * EDIM + e) * ADIM + n]
                             : Wk[(m * EDIM + e) * ADIM + (n - ADIM)];
        wqk[idx] = f2b(f);
    }
    for (int idx = i; idx < MOD * 1024 * EDIM; idx += stride) {
        int k = idx / (1024 * EDIM); int r = idx % (1024 * EDIM);
        int n = r / EDIM; int e = r % EDIM;
        int q = (n < EDIM) ? (k + 1) % 3 : (k + 2) % 3;
        int f = (n < EDIM) ? n : n - EDIM;
        wtt2[idx] = f2b(Wt[((size_t)(q * 3 + k) * EDIM + e) * EDIM + f]);
    }
}

// ================= 256x256-tile phase-split GEMM core =================
// 8 waves (wm = wid>>2 in {0,1}, wn = wid&3), per-wave C = 128x64.
// K-tile = 64 split into 2 K-halves of 32. Staging unit = (operand, K-half)
// = [256 rows][32 cols] bf16 = 16 KB. Ring of 8 slots = 128 KB LDS.
// Stream s = 4t + 2*ks + opB. Stage 6 units ahead (unit s issued in phase s-6).
// 4 phases per K-tile (q = 2*ks + rh), 16 MFMA each. Waits: vmcnt(2*allow)
// at q0/q2 only; allow=5 steady, tail ledgered (see do_tile calls).
// LDS swizzle: 16B-group g stored at g ^ ((row>>1)&3), applied on BOTH the
// pre-swizzled global source and the ds_read offset (involution).

struct GCtx {
    const unsigned short* pA;   // per-thread staging src (row & swizzle applied)
    const unsigned short* pB;
    const unsigned short* lds;  // read base
    unsigned short* ldsW;       // stage dest wave base = lds + wid*1024
    int aoff, boff;             // per-thread fragment read offsets (elems)
};

__device__ __forceinline__ void stage_s(const GCtx& c, int s) {
    if (s >= 32) return;                       // 8 K-tiles * 4 units
    int colK = (s >> 2) * 64 + (s & 2) * 16;   // K-column of this unit
    const unsigned short* src = ((s & 1) ? c.pB : c.pA) + colK;
    unsigned short* dst = c.ldsW + (s & 7) * 8192;
    glds16(src, dst);
    glds16(src + 16 * 512, dst + 512);
}

template<int Q>
__device__ __forceinline__ void phase_compute(int T, const GCtx& c,
                                              s16x8 (&bfr)[4], f32x4 (&acc)[8][4]) {
    constexpr int ks = Q >> 1, rh = Q & 1;
    const unsigned short* Asl = c.lds + ((T & 1) * 4 + 2 * ks) * 8192;
    const unsigned short* Bsl = Asl + 8192;
    s16x8 af[4];
#pragma unroll
    for (int i = 0; i < 4; ++i) af[i] = *(const s16x8*)(Asl + c.aoff + (rh * 4 + i) * 512);
    if constexpr ((Q & 1) == 0) {
#pragma unroll
        for (int j = 0; j < 4; ++j) bfr[j] = *(const s16x8*)(Bsl + c.boff + j * 512);
    }
    __builtin_amdgcn_s_setprio(1);
#pragma unroll
    for (int i = 0; i < 4; ++i)
#pragma unroll
        for (int j = 0; j < 4; ++j)
            acc[rh * 4 + i][j] = __builtin_amdgcn_mfma_f32_16x16x32_bf16(
                __builtin_bit_cast(bf16x8, af[i]), __builtin_bit_cast(bf16x8, bfr[j]),
                acc[rh * 4 + i][j], 0, 0, 0);
    __builtin_amdgcn_s_setprio(0);
}

template<int W0, int W2>
__device__ __forceinline__ void do_tile(int T, const GCtx& c,
                                        s16x8 (&bfr)[4], f32x4 (&acc)[8][4]) {
    stage_s(c, 4 * T + 6);           // q0
    WAITV(W0); BAR();
    phase_compute<0>(T, c, bfr, acc);
    BAR();
    stage_s(c, 4 * T + 7);           // q1
    phase_compute<1>(T, c, bfr, acc);
    BAR();
    stage_s(c, 4 * T + 8);           // q2
    WAITV(W2); BAR();
    phase_compute<2>(T, c, bfr, acc);
    BAR();
    stage_s(c, 4 * T + 9);           // q3
    phase_compute<3>(T, c, bfr, acc);
    BAR();
}

__device__ __forceinline__ void gemm256_core(const unsigned short* Ag,
                                             const unsigned short* Bg,
                                             unsigned short* lds, f32x4 (&acc)[8][4]) {
    const int tid = threadIdx.x, lane = tid & 63, wid = tid >> 6;
    const int wm = wid >> 2, wn = wid & 3;
    GCtx c;
    int stageRow = wid * 32 + (lane >> 2);
    int gsrc8 = ((lane & 3) ^ ((lane >> 3) & 3)) * 8;
    c.pA = Ag + (size_t)stageRow * 512 + gsrc8;
    c.pB = Bg + (size_t)stageRow * 512 + gsrc8;
    c.lds = lds;
    c.ldsW = lds + wid * 1024;
    int swz8 = ((lane >> 4) ^ ((lane >> 1) & 3)) * 8;
    c.aoff = (wm * 128 + (lane & 15)) * 32 + swz8;
    c.boff = (wn * 64 + (lane & 15)) * 32 + swz8;
    s16x8 bfr[4];
#pragma unroll
    for (int s = 0; s < 6; ++s) stage_s(c, s);   // prologue: Kt0 all, Kt1 A0,B0
#pragma unroll 1
    for (int t = 0; t < 6; ++t) do_tile<10, 10>(t, c, bfr, acc);
    do_tile<10, 8>(6, c, bfr, acc);
    do_tile<4, 0>(7, c, bfr, acc);
}

// ============ kernel 2: proj = X_m @ [Wq|Wk]_m + bias, bf16 out ============
__global__ __launch_bounds__(512, 2) void k_gemm_proj(const unsigned short* __restrict__ xb,
                                                      const unsigned short* __restrict__ wqk,
                                                      const float* __restrict__ bq,
                                                      const float* __restrict__ bk,
                                                      unsigned short* __restrict__ proj) {
    __shared__ __align__(16) unsigned short LDS[65536];
    int l = (blockIdx.x & 7) * 192 + (blockIdx.x >> 3);   // XCD-chunked, nwg=1536
    int ct = l & 1, rt = (l >> 1) & 255, m = l >> 9;
    int row0 = rt * 256, col0 = ct * 256;
    f32x4 acc[8][4];
#pragma unroll
    for (int i = 0; i < 8; ++i) for (int j = 0; j < 4; ++j) acc[i][j] = (f32x4)0.f;
    gemm256_core(xb + ((size_t)m * BATCH + row0) * EDIM,
                 wqk + ((size_t)m * EDIM + col0) * EDIM, LDS, acc);
    int lane = threadIdx.x & 63, wid = threadIdx.x >> 6;
    int wm = wid >> 2, wn = wid & 3;
#pragma unroll
    for (int j = 0; j < 4; ++j) {
        int col = col0 + wn * 64 + j * 16 + (lane & 15);
        float bias = (col < ADIM) ? bq[m * ADIM + col] : bk[m * ADIM + col - ADIM];
#pragma unroll
        for (int i8 = 0; i8 < 8; ++i8) {
            int rbase = row0 + wm * 128 + i8 * 16 + (lane >> 4) * 4;
#pragma unroll
            for (int r = 0; r < 4; ++r)
                proj[((size_t)m * BATCH + rbase + r) * EDIM + col] = f2b(acc[i8][j][r] + bias);
        }
    }
}

// ============ kernel 3: scores + softmax -> alpha[q*2+ki][b], k=(q+1+ki)%3 ============
__global__ __launch_bounds__(256) void k_scores(const unsigned short* __restrict__ proj,
                                                const float* __restrict__ v,
                                                float* __restrict__ alpha) {
    int wid = threadIdx.x >> 6, lane = threadIdx.x & 63;
    size_t b = (size_t)blockIdx.x * 4 + wid;
    float qp[3][4], kp[3][4], vq[3][4];
    for (int m = 0; m < 3; ++m) {
        const unsigned short* p = proj + ((size_t)m * BATCH + b) * EDIM;
        u16x4 uq = *(const u16x4*)(p + lane * 4);
        u16x4 uk = *(const u16x4*)(p + ADIM + lane * 4);
        f32x4 vv = *((const f32x4*)(v + m * ADIM) + lane);
        for (int j = 0; j < 4; ++j) { qp[m][j] = b2f(uq[j]); kp[m][j] = b2f(uk[j]); vq[m][j] = vv[j]; }
    }
    for (int q = 0; q < 3; ++q) {
        float s[2];
        for (int ki = 0; ki < 2; ++ki) {
            int k = (q + 1 + ki) % 3;
            float a = 0.f;
            for (int j = 0; j < 4; ++j) a += vq[q][j] * tanhf(qp[q][j] + kp[k][j]);
            for (int off = 32; off; off >>= 1) a += __shfl_xor(a, off, 64);
            s[ki] = a;
        }
        if (lane == 0) {
            float mx = fmaxf(s[0], s[1]);
            float e0 = expf(s[0] - mx), e1 = expf(s[1] - mx);
            float inv = 1.f / (e0 + e1);
            alpha[(size_t)(q * 2 + 0) * BATCH + b] = e0 * inv;
            alpha[(size_t)(q * 2 + 1) * BATCH + b] = e1 * inv;
        }
    }
}

// ============ kernel 4: Y[k] = X_k @ wtt2[k]  (N=1024 pure GEMM) ============
__global__ __launch_bounds__(512, 2) void k_gemm_y(const unsigned short* __restrict__ xb,
                                                   const unsigned short* __restrict__ wtt2,
                                                   unsigned short* __restrict__ y) {
    __shared__ __align__(16) unsigned short LDS[65536];
    int l = (blockIdx.x & 7) * 384 + (blockIdx.x >> 3);   // XCD-chunked, nwg=3072
    int ct = l & 3, rt = (l >> 2) & 255, k = l >> 10;
    int row0 = rt * 256, col0 = ct * 256;
    f32x4 acc[8][4];
#pragma unroll
    for (int i = 0; i < 8; ++i) for (int j = 0; j < 4; ++j) acc[i][j] = (f32x4)0.f;
    gemm256_core(xb + ((size_t)k * BATCH + row0) * EDIM,
                 wtt2 + ((size_t)k * 1024 + col0) * EDIM, LDS, acc);
    int lane = threadIdx.x & 63, wid = threadIdx.x >> 6;
    int wm = wid >> 2, wn = wid & 3;
    int p  = (ct < 2) ? (((k + 1) % 3) * 2 + 1) : (((k + 2) % 3) * 2 + 0);
    int cb = (ct < 2) ? col0 : (col0 - EDIM);
#pragma unroll
    for (int j = 0; j < 4; ++j) {
        int col = cb + wn * 64 + j * 16 + (lane & 15);
#pragma unroll
        for (int i8 = 0; i8 < 8; ++i8) {
            int rbase = row0 + wm * 128 + i8 * 16 + (lane >> 4) * 4;
#pragma unroll
            for (int r = 0; r < 4; ++r)
                y[((size_t)p * BATCH + rbase + r) * EDIM + col] = f2b(acc[i8][j][r]);
        }
    }
}

// ============ kernel 5: out = LN(xb + a0*(Y0+bt0) + a1*(Y1+bt1)) ============
__global__ __launch_bounds__(192) void k_fuse_ln(const unsigned short* __restrict__ xb,
                                                 const unsigned short* __restrict__ y,
                                                 const float* __restrict__ alpha,
                                                 const float* __restrict__ bt,
                                                 const float* __restrict__ gamma,
                                                 const float* __restrict__ beta,
                                                 float* __restrict__ out) {
    __shared__ float red[2][3];
    int b = blockIdx.x, t = threadIdx.x, m = t >> 6, lane = t & 63;
    int e0 = lane * 8;
    float a0 = alpha[(size_t)(m * 2 + 0) * BATCH + b];
    float a1 = alpha[(size_t)(m * 2 + 1) * BATCH + b];
    s16x8 xv = *(const s16x8*)(xb + ((size_t)m * BATCH + b) * EDIM + e0);
    s16x8 y0 = *(const s16x8*)(y + ((size_t)(m * 2 + 0) * BATCH + b) * EDIM + e0);
    s16x8 y1 = *(const s16x8*)(y + ((size_t)(m * 2 + 1) * BATCH + b) * EDIM + e0);
    int kA = (m + 1) % 3, kB = (m + 2) % 3;
    const float* bA = bt + (size_t)(m * 3 + kA) * EDIM + e0;
    const float* bB = bt + (size_t)(m * 3 + kB) * EDIM + e0;
    f32x4 bA0 = *(const f32x4*)bA, bA1 = *(const f32x4*)(bA + 4);
    f32x4 bB0 = *(const f32x4*)bB, bB1 = *(const f32x4*)(bB + 4);
    float v[8]; float s = 0.f, s2 = 0.f;
#pragma unroll
    for (int j = 0; j < 8; ++j) {
        float ba = (j < 4) ? bA0[j] : bA1[j - 4];
        float bb = (j < 4) ? bB0[j] : bB1[j - 4];
        float vv = b2f((unsigned short)xv[j]) + a0 * (b2f((unsigned short)y0[j]) + ba)
                                             + a1 * (b2f((unsigned short)y1[j]) + bb);
        v[j] = vv; s += vv; s2 += vv * vv;
    }
    for (int off = 32; off; off >>= 1) { s += __shfl_xor(s, off, 64); s2 += __shfl_xor(s2, off, 64); }
    if (lane == 0) { red[0][m] = s; red[1][m] = s2; }
    __syncthreads();
    float S = red[0][0] + red[0][1] + red[0][2];
    float S2 = red[1][0] + red[1][1] + red[1][2];
    float mu  = S * (1.f / 1536.f);
    float var = S2 * (1.f / 1536.f) - mu * mu;
    float rs  = rsqrtf(var + 1e-5f);
    int f0 = m * EDIM + e0;
    f32x4 g0 = *(const f32x4*)(gamma + f0), g1 = *(const f32x4*)(gamma + f0 + 4);
    f32x4 be0 = *(const f32x4*)(beta + f0), be1 = *(const f32x4*)(beta + f0 + 4);
    f32x4 o0, o1;
#pragma unroll
    for (int j = 0; j < 4; ++j) {
        o0[j] = (v[j]     - mu) * rs * g0[j] + be0[j];
        o1[j] = (v[j + 4] - mu) * rs * g1[j] + be1[j];
    }
    float* op = out + (size_t)b * FEAT + f0;
    *(f32x4*)op = o0; *(f32x4*)(op + 4) = o1;
}

// ============ launcher ============
extern "C" void kernel_launch(void* const* d_in, const int* in_sizes, int n_in,
                              void* d_out, int out_size, void* d_ws, size_t ws_size,
                              hipStream_t stream) {
    const float* x     = (const float*)d_in[0];
    const float* Wq    = (const float*)d_in[1];
    const float* bq    = (const float*)d_in[2];
    const float* Wk    = (const float*)d_in[3];
    const float* bk    = (const float*)d_in[4];
    const float* v     = (const float*)d_in[5];
    const float* Wt    = (const float*)d_in[6];
    const float* bt    = (const float*)d_in[7];
    const float* gamma = (const float*)d_in[8];
    const float* beta  = (const float*)d_in[9];
    float* out = (float*)d_out;

    char* ws = (char*)d_ws;
    unsigned short* wqk   = (unsigned short*)(ws);
    unsigned short* wtt2  = (unsigned short*)(ws + 1572864);
    float*          alpha = (float*)        (ws + 4718592);
    unsigned short* xb    = (unsigned short*)(ws + 6291456);
    unsigned short* y     = (unsigned short*)(ws + 207618048);
    unsigned short* proj  = y;  // proj fully consumed by k_scores before k_gemm_y writes y

    k_convert_x<<<4096, 256, 0, stream>>>(x, xb, (MOD * BATCH * EDIM) / 4);
    k_prep_w   <<<2048, 256, 0, stream>>>(Wq, Wk, Wt, wqk, wtt2);
    k_gemm_proj<<<1536, 512, 0, stream>>>(xb, wqk, bq, bk, proj);
    k_scores   <<<16384, 256, 0, stream>>>(proj, v, alpha);
    k_gemm_y   <<<3072, 512, 0, stream>>>(xb, wtt2, y);
    k_fuse_ln  <<<65536, 192, 0, stream>>>(xb, y, alpha, bt, gamma, beta, out);
}

// Round 5
// 751.106 us; speedup vs baseline: 1.3190x; 1.1979x over previous
//
#include <hip/hip_runtime.h>
#include <hip/hip_bf16.h>

// ---- problem constants ----
#define MOD   3
#define BATCH 65536
#define EDIM  512
#define ADIM  256
#define FEAT  1536   // MOD*EDIM

// ---- types ----
typedef __attribute__((ext_vector_type(8))) short   s16x8;
typedef __attribute__((ext_vector_type(8))) __bf16  bf16x8;
typedef __attribute__((ext_vector_type(4))) float   f32x4;
typedef __attribute__((ext_vector_type(4))) unsigned short u16x4;

__device__ __forceinline__ float b2f(unsigned short u) {
    union { unsigned int ui; float f; } c; c.ui = ((unsigned int)u) << 16; return c.f;
}
__device__ __forceinline__ unsigned short f2b(float f) {
    __hip_bfloat16 h = __float2bfloat16(f);
    return __builtin_bit_cast(unsigned short, h);
}

// async global->LDS, 16B per lane (wave-uniform LDS base; HW adds lane*16)
__device__ __forceinline__ void glds16(const unsigned short* g, unsigned short* l) {
    __builtin_amdgcn_global_load_lds(
        (const __attribute__((address_space(1))) void*)g,
        (__attribute__((address_space(3))) void*)l, 16, 0, 0);
}

#define WAITV(N) asm volatile("s_waitcnt vmcnt(%0)" :: "i"(N) : "memory")
__device__ __forceinline__ void BAR() {
    asm volatile("" ::: "memory");
    __builtin_amdgcn_s_barrier();
    asm volatile("" ::: "memory");
}

// ============ kernel 0: x f32 -> bf16 bits ============
__global__ __launch_bounds__(256) void k_convert_x(const float* __restrict__ x,
                                                   unsigned short* __restrict__ xb, int n4) {
    int i = blockIdx.x * blockDim.x + threadIdx.x;
    int stride = gridDim.x * blockDim.x;
    for (; i < n4; i += stride) {
        f32x4 v = *((const f32x4*)x + i);
        u16x4 o;
        for (int j = 0; j < 4; ++j) o[j] = f2b(v[j]);
        *((u16x4*)xb + i) = o;
    }
}

// ============ kernel 1: weight prep ============
// wqk [m][n(512)][e]:  n<256 -> Wq[m][e][n] else Wk[m][e][n-256]
// wtt3[q][k'(2)][f(512)][e]: k' = 0 -> k=(q+1)%3, k'=1 -> k=(q+2)%3;  = Wt[q][k][e][f]
__global__ __launch_bounds__(256) void k_prep_w(const float* __restrict__ Wq,
                                                const float* __restrict__ Wk,
                                                const float* __restrict__ Wt,
                                                unsigned short* __restrict__ wqk,
                                                unsigned short* __restrict__ wtt3) {
    int i = blockIdx.x * blockDim.x + threadIdx.x;
    int stride = gridDim.x * blockDim.x;
    for (int idx = i; idx < MOD * EDIM * EDIM; idx += stride) {
        int m = idx / (EDIM * EDIM); int r = idx % (EDIM * EDIM);
        int n = r / EDIM; int e = r % EDIM;
        float f = (n < ADIM) ? Wq[(m * EDIM + e) * ADIM + n]
                             : Wk[(m * EDIM + e) * ADIM + (n - ADIM)];
        wqk[idx] = f2b(f);
    }
    for (int idx = i; idx < MOD * 1024 * EDIM; idx += stride) {
        int q = idx / (1024 * EDIM); int r = idx % (1024 * EDIM);
        int n = r / EDIM; int e = r % EDIM;
        int kp = n >> 9, f = n & 511;
        int k = (q + 1 + kp) % 3;
        wtt3[idx] = f2b(Wt[((size_t)(q * 3 + k) * EDIM + e) * EDIM + f]);
    }
}

// ================= 256x256-tile phase-split GEMM core =================
// 8 waves (wm=wid>>2, wn=wid&3), per-wave C = 128x64. K-tile = 64, 2 K-halves.
// Staging unit = (operand, K-half) = [256][32] bf16 = 16 KB; ring of 8 = 128 KB.
// Stream s = 4t + 2*ks + opB, panel = s>>5 (dual-panel K=1024 support).
// Stage 6 units ahead; waits vmcnt(2*units_allowed) at q0/q2 only.
// LDS swizzle: group g stored at g ^ ((row>>1)&3), both-sides involution.

struct GCtx {
    const unsigned short* pA[2];
    const unsigned short* pB[2];
    const unsigned short* lds;
    unsigned short* ldsW;
    int aoff, boff;
};

__device__ __forceinline__ void gctx_init(GCtx& c,
                                          const unsigned short* Ag0, const unsigned short* Ag1,
                                          const unsigned short* Bg0, const unsigned short* Bg1,
                                          unsigned short* lds) {
    const int tid = threadIdx.x, lane = tid & 63, wid = tid >> 6;
    const int wm = wid >> 2, wn = wid & 3;
    int stageRow = wid * 32 + (lane >> 2);
    int gsrc8 = ((lane & 3) ^ ((lane >> 3) & 3)) * 8;
    size_t so = (size_t)stageRow * 512 + gsrc8;
    c.pA[0] = Ag0 + so; c.pA[1] = Ag1 + so;
    c.pB[0] = Bg0 + so; c.pB[1] = Bg1 + so;
    c.lds = lds;
    c.ldsW = lds + wid * 1024;
    int swz8 = ((lane >> 4) ^ ((lane >> 1) & 3)) * 8;
    c.aoff = (wm * 128 + (lane & 15)) * 32 + swz8;
    c.boff = (wn * 64 + (lane & 15)) * 32 + swz8;
}

template<int NU>
__device__ __forceinline__ void stage_s(const GCtx& c, int s) {
    if (s >= NU) return;
    int p = s >> 5;
    int sp = s & 31;
    int colK = (sp >> 2) * 64 + (sp & 2) * 16;
    const unsigned short* src = ((sp & 1) ? c.pB[p] : c.pA[p]) + colK;
    unsigned short* dst = c.ldsW + (s & 7) * 8192;
    glds16(src, dst);
    glds16(src + 16 * 512, dst + 512);
}

template<int Q>
__device__ __forceinline__ void phase_compute(int T, const GCtx& c,
                                              s16x8 (&bfr)[4], f32x4 (&acc)[8][4]) {
    constexpr int ks = Q >> 1, rh = Q & 1;
    const unsigned short* Asl = c.lds + ((T & 1) * 4 + 2 * ks) * 8192;
    const unsigned short* Bsl = Asl + 8192;
    s16x8 af[4];
#pragma unroll
    for (int i = 0; i < 4; ++i) af[i] = *(const s16x8*)(Asl + c.aoff + (rh * 4 + i) * 512);
    if constexpr ((Q & 1) == 0) {
#pragma unroll
        for (int j = 0; j < 4; ++j) bfr[j] = *(const s16x8*)(Bsl + c.boff + j * 512);
    }
    __builtin_amdgcn_s_setprio(1);
#pragma unroll
    for (int i = 0; i < 4; ++i)
#pragma unroll
        for (int j = 0; j < 4; ++j)
            acc[rh * 4 + i][j] = __builtin_amdgcn_mfma_f32_16x16x32_bf16(
                __builtin_bit_cast(bf16x8, af[i]), __builtin_bit_cast(bf16x8, bfr[j]),
                acc[rh * 4 + i][j], 0, 0, 0);
    __builtin_amdgcn_s_setprio(0);
}

template<int W0, int W2, int NU>
__device__ __forceinline__ void do_tile(int T, const GCtx& c,
                                        s16x8 (&bfr)[4], f32x4 (&acc)[8][4]) {
    stage_s<NU>(c, 4 * T + 6);       // q0
    WAITV(W0); BAR();
    phase_compute<0>(T, c, bfr, acc);
    BAR();
    stage_s<NU>(c, 4 * T + 7);       // q1
    phase_compute<1>(T, c, bfr, acc);
    BAR();
    stage_s<NU>(c, 4 * T + 8);       // q2
    WAITV(W2); BAR();
    phase_compute<2>(T, c, bfr, acc);
    BAR();
    stage_s<NU>(c, 4 * T + 9);       // q3
    phase_compute<3>(T, c, bfr, acc);
    BAR();
}

// ============ kernel 2: proj = X_m @ [Wq|Wk]_m + bias, bf16 out ============
__global__ __launch_bounds__(512, 2) void k_gemm_proj(const unsigned short* __restrict__ xb,
                                                      const unsigned short* __restrict__ wqk,
                                                      const float* __restrict__ bq,
                                                      const float* __restrict__ bk,
                                                      unsigned short* __restrict__ proj) {
    __shared__ __align__(16) unsigned short LDS[65536];
    int l = (blockIdx.x & 7) * 192 + (blockIdx.x >> 3);   // XCD-chunked, nwg=1536
    int ct = l & 1, rt = (l >> 1) & 255, m = l >> 9;
    int row0 = rt * 256, col0 = ct * 256;
    f32x4 acc[8][4];
#pragma unroll
    for (int i = 0; i < 8; ++i) for (int j = 0; j < 4; ++j) acc[i][j] = (f32x4)0.f;
    GCtx c;
    const unsigned short* Ag = xb + ((size_t)m * BATCH + row0) * EDIM;
    const unsigned short* Bg = wqk + ((size_t)m * EDIM + col0) * EDIM;
    gctx_init(c, Ag, Ag, Bg, Bg, LDS);
    s16x8 bfr[4];
#pragma unroll
    for (int s = 0; s < 6; ++s) stage_s<32>(c, s);
#pragma unroll 1
    for (int t = 0; t < 6; ++t) do_tile<10, 10, 32>(t, c, bfr, acc);
    do_tile<10, 8, 32>(6, c, bfr, acc);
    do_tile<4, 0, 32>(7, c, bfr, acc);
    int lane = threadIdx.x & 63, wid = threadIdx.x >> 6;
    int wm = wid >> 2, wn = wid & 3;
#pragma unroll
    for (int j = 0; j < 4; ++j) {
        int col = col0 + wn * 64 + j * 16 + (lane & 15);
        float bias = (col < ADIM) ? bq[m * ADIM + col] : bk[m * ADIM + col - ADIM];
#pragma unroll
        for (int i8 = 0; i8 < 8; ++i8) {
            int rbase = row0 + wm * 128 + i8 * 16 + (lane >> 4) * 4;
#pragma unroll
            for (int r = 0; r < 4; ++r)
                proj[((size_t)m * BATCH + rbase + r) * EDIM + col] = f2b(acc[i8][j][r] + bias);
        }
    }
}

// ============ kernel 3: scores + softmax -> alpha[q*2+ki][b], k=(q+1+ki)%3 ============
__global__ __launch_bounds__(256) void k_scores(const unsigned short* __restrict__ proj,
                                                const float* __restrict__ v,
                                                float* __restrict__ alpha) {
    int wid = threadIdx.x >> 6, lane = threadIdx.x & 63;
    size_t b = (size_t)blockIdx.x * 4 + wid;
    float qp[3][4], kp[3][4], vq[3][4];
    for (int m = 0; m < 3; ++m) {
        const unsigned short* p = proj + ((size_t)m * BATCH + b) * EDIM;
        u16x4 uq = *(const u16x4*)(p + lane * 4);
        u16x4 uk = *(const u16x4*)(p + ADIM + lane * 4);
        f32x4 vv = *((const f32x4*)(v + m * ADIM) + lane);
        for (int j = 0; j < 4; ++j) { qp[m][j] = b2f(uq[j]); kp[m][j] = b2f(uk[j]); vq[m][j] = vv[j]; }
    }
    for (int q = 0; q < 3; ++q) {
        float s[2];
        for (int ki = 0; ki < 2; ++ki) {
            int k = (q + 1 + ki) % 3;
            float a = 0.f;
            for (int j = 0; j < 4; ++j) a += vq[q][j] * tanhf(qp[q][j] + kp[k][j]);
            for (int off = 32; off; off >>= 1) a += __shfl_xor(a, off, 64);
            s[ki] = a;
        }
        if (lane == 0) {
            float mx = fmaxf(s[0], s[1]);
            float e0 = expf(s[0] - mx), e1 = expf(s[1] - mx);
            float inv = 1.f / (e0 + e1);
            alpha[(size_t)(q * 2 + 0) * BATCH + b] = e0 * inv;
            alpha[(size_t)(q * 2 + 1) * BATCH + b] = e1 * inv;
        }
    }
}

// ============ kernel 4: att[q] = a0*(X_kA@WtA + btA) + a1*(X_kB@WtB + btB) ============
// Dual-panel K=1024 with single acc via ratio trick:
//   acc = (a0/a1)*P0 after panel 0, += P1, final scale a1.
__global__ __launch_bounds__(512, 2) void k_gemm_att(const unsigned short* __restrict__ xb,
                                                     const unsigned short* __restrict__ wtt3,
                                                     const float* __restrict__ alpha,
                                                     const float* __restrict__ bt,
                                                     unsigned short* __restrict__ att) {
    __shared__ __align__(16) unsigned short LDS[65536];
    __shared__ float auxA0[256], auxA1[256], auxR[256];
    int l = (blockIdx.x & 7) * 192 + (blockIdx.x >> 3);   // XCD-chunked, nwg=1536
    int ct = l & 1, rt = (l >> 1) & 255, q = l >> 9;
    int row0 = rt * 256, col0 = ct * 256;
    int kA = (q + 1) % 3, kB = (q + 2) % 3;
    int tid = threadIdx.x, lane = tid & 63, wid = tid >> 6;
    int wm = wid >> 2, wn = wid & 3;

    if (tid < 256) {
        float a0 = alpha[(size_t)(q * 2 + 0) * BATCH + row0 + tid];
        float a1 = alpha[(size_t)(q * 2 + 1) * BATCH + row0 + tid];
        auxA0[tid] = a0; auxA1[tid] = a1;
        auxR[tid] = a0 / fmaxf(a1, 1e-30f);
    }
    __syncthreads();   // drains vmcnt(0): stage ledger starts clean

    f32x4 acc[8][4];
#pragma unroll
    for (int i = 0; i < 8; ++i) for (int j = 0; j < 4; ++j) acc[i][j] = (f32x4)0.f;
    GCtx c;
    gctx_init(c,
              xb + ((size_t)kA * BATCH + row0) * EDIM,
              xb + ((size_t)kB * BATCH + row0) * EDIM,
              wtt3 + ((size_t)(q * 2 + 0) * EDIM + col0) * EDIM,
              wtt3 + ((size_t)(q * 2 + 1) * EDIM + col0) * EDIM,
              LDS);
    s16x8 bfr[4];
#pragma unroll
    for (int s = 0; s < 6; ++s) stage_s<64>(c, s);
#pragma unroll 1
    for (int t = 0; t < 8; ++t) do_tile<10, 10, 64>(t, c, bfr, acc);
    // ---- mid-scale: acc *= a0/a1 per row (panel boundary; registers only) ----
#pragma unroll
    for (int i8 = 0; i8 < 8; ++i8) {
        int rl = wm * 128 + i8 * 16 + (lane >> 4) * 4;
        f32x4 rv = *(const f32x4*)&auxR[rl];
#pragma unroll
        for (int j = 0; j < 4; ++j)
#pragma unroll
            for (int r = 0; r < 4; ++r) acc[i8][j][r] *= rv[r];
    }
#pragma unroll 1
    for (int t = 8; t < 14; ++t) do_tile<10, 10, 64>(t, c, bfr, acc);
    do_tile<10, 8, 64>(14, c, bfr, acc);
    do_tile<4, 0, 64>(15, c, bfr, acc);

    // ---- epilogue: att = a1*acc + a0*btA[col] + a1*btB[col] ----
    float btAv[4], btBv[4];
#pragma unroll
    for (int j = 0; j < 4; ++j) {
        int col = col0 + wn * 64 + j * 16 + (lane & 15);
        btAv[j] = bt[(size_t)(q * 3 + kA) * EDIM + col];
        btBv[j] = bt[(size_t)(q * 3 + kB) * EDIM + col];
    }
#pragma unroll
    for (int i8 = 0; i8 < 8; ++i8) {
        int rl = wm * 128 + i8 * 16 + (lane >> 4) * 4;
        f32x4 a0v = *(const f32x4*)&auxA0[rl];
        f32x4 a1v = *(const f32x4*)&auxA1[rl];
        int rbase = row0 + rl;
#pragma unroll
        for (int j = 0; j < 4; ++j) {
            int col = col0 + wn * 64 + j * 16 + (lane & 15);
#pragma unroll
            for (int r = 0; r < 4; ++r)
                att[((size_t)q * BATCH + rbase + r) * EDIM + col] =
                    f2b(a1v[r] * acc[i8][j][r] + a0v[r] * btAv[j] + a1v[r] * btBv[j]);
        }
    }
}

// ============ kernel 5: out = LN(xb + att) ============
__global__ __launch_bounds__(192) void k_fuse_ln(const unsigned short* __restrict__ xb,
                                                 const unsigned short* __restrict__ att,
                                                 const float* __restrict__ gamma,
                                                 const float* __restrict__ beta,
                                                 float* __restrict__ out) {
    __shared__ float red[2][3];
    int b = blockIdx.x, t = threadIdx.x, m = t >> 6, lane = t & 63;
    int e0 = lane * 8;
    s16x8 xv = *(const s16x8*)(xb + ((size_t)m * BATCH + b) * EDIM + e0);
    s16x8 av = *(const s16x8*)(att + ((size_t)m * BATCH + b) * EDIM + e0);
    float v[8]; float s = 0.f, s2 = 0.f;
#pragma unroll
    for (int j = 0; j < 8; ++j) {
        float vv = b2f((unsigned short)xv[j]) + b2f((unsigned short)av[j]);
        v[j] = vv; s += vv; s2 += vv * vv;
    }
    for (int off = 32; off; off >>= 1) { s += __shfl_xor(s, off, 64); s2 += __shfl_xor(s2, off, 64); }
    if (lane == 0) { red[0][m] = s; red[1][m] = s2; }
    __syncthreads();
    float S = red[0][0] + red[0][1] + red[0][2];
    float S2 = red[1][0] + red[1][1] + red[1][2];
    float mu  = S * (1.f / 1536.f);
    float var = S2 * (1.f / 1536.f) - mu * mu;
    float rs  = rsqrtf(var + 1e-5f);
    int f0 = m * EDIM + e0;
    f32x4 g0 = *(const f32x4*)(gamma + f0), g1 = *(const f32x4*)(gamma + f0 + 4);
    f32x4 be0 = *(const f32x4*)(beta + f0), be1 = *(const f32x4*)(beta + f0 + 4);
    f32x4 o0, o1;
#pragma unroll
    for (int j = 0; j < 4; ++j) {
        o0[j] = (v[j]     - mu) * rs * g0[j] + be0[j];
        o1[j] = (v[j + 4] - mu) * rs * g1[j] + be1[j];
    }
    float* op = out + (size_t)b * FEAT + f0;
    *(f32x4*)op = o0; *(f32x4*)(op + 4) = o1;
}

// ============ launcher ============
extern "C" void kernel_launch(void* const* d_in, const int* in_sizes, int n_in,
                              void* d_out, int out_size, void* d_ws, size_t ws_size,
                              hipStream_t stream) {
    const float* x     = (const float*)d_in[0];
    const float* Wq    = (const float*)d_in[1];
    const float* bq    = (const float*)d_in[2];
    const float* Wk    = (const float*)d_in[3];
    const float* bk    = (const float*)d_in[4];
    const float* v     = (const float*)d_in[5];
    const float* Wt    = (const float*)d_in[6];
    const float* bt    = (const float*)d_in[7];
    const float* gamma = (const float*)d_in[8];
    const float* beta  = (const float*)d_in[9];
    float* out = (float*)d_out;

    char* ws = (char*)d_ws;
    // layout (bytes):
    //   [0,         1572864)  wqk   bf16 3*512*512
    //   [1572864,   4718592)  wtt3  bf16 3*1024*512
    //   [4718592,   6291456)  alpha f32  6*65536
    //   [6291456, 207618048)  xb    bf16 3*65536*512
    //   [207618048,408944640) att   bf16 3*65536*512  (proj aliases; consumed first)
    unsigned short* wqk   = (unsigned short*)(ws);
    unsigned short* wtt3  = (unsigned short*)(ws + 1572864);
    float*          alpha = (float*)        (ws + 4718592);
    unsigned short* xb    = (unsigned short*)(ws + 6291456);
    unsigned short* att   = (unsigned short*)(ws + 207618048);
    unsigned short* proj  = att;  // proj fully consumed by k_scores before k_gemm_att writes att

    k_convert_x<<<4096, 256, 0, stream>>>(x, xb, (MOD * BATCH * EDIM) / 4);
    k_prep_w   <<<2048, 256, 0, stream>>>(Wq, Wk, Wt, wqk, wtt3);
    k_gemm_proj<<<1536, 512, 0, stream>>>(xb, wqk, bq, bk, proj);
    k_scores   <<<16384, 256, 0, stream>>>(proj, v, alpha);
    k_gemm_att <<<1536, 512, 0, stream>>>(xb, wtt3, alpha, bt, att);
    k_fuse_ln  <<<65536, 192, 0, stream>>>(xb, att, gamma, beta, out);
}